// Round 1
// baseline (694.299 us; speedup 1.0000x reference)
//
#include <hip/hip_runtime.h>
#include <math.h>

#define N_NODES 50000
#define N_EDGES 400000
#define IN_DIM 192
#define TIME_DIM 64
#define GAT_IN 256
#define OUT_DIM 256

// ---------------- edge time encoding + mean aggregation ----------------
// wave (64 lanes) owns 64 time dims; each wave loops over EPW edges.
__global__ void k_edge_time(const float* __restrict__ time_t, const int* __restrict__ dst,
                            const float* __restrict__ tw, const float* __restrict__ tb,
                            float* __restrict__ agg, float* __restrict__ deg) {
    const int EPW = 16;
    int lane = threadIdx.x & 63;
    int wave = threadIdx.x >> 6;
    int base = (blockIdx.x * 4 + wave) * EPW;
    float w = tw[lane], b = tb[lane];
    for (int i = 0; i < EPW; ++i) {
        int e = base + i;
        if (e >= N_EDGES) return;
        float t = time_t[e];
        int d = dst[e];
        float v = __cosf(t * w + b);
        atomicAdd(&agg[d * 64 + lane], v);
        if (lane == 0) atomicAdd(&deg[d], 1.0f);
    }
}

// ---------------- combined = [h | agg/deg]  -> d_out (residual base + GEMM input)
__global__ void k_combine(const float* __restrict__ h, const float* __restrict__ agg,
                          const float* __restrict__ deg, float* __restrict__ out) {
    int n = blockIdx.x;
    int t = threadIdx.x;
    float v;
    if (t < IN_DIM) v = h[n * IN_DIM + t];
    else            v = agg[n * 64 + (t - IN_DIM)] / fmaxf(deg[n], 1.0f);
    out[n * 256 + t] = v;
}

// ---------------- feat = combined @ fc_w ; el/er fused wave reductions ----------------
// 256 threads, 16 nodes per block. Thread t owns output column t for all 16 nodes.
// combined rows read via block-uniform (scalar) loads; fc_w rows coalesced.
__global__ __launch_bounds__(256) void k_gemm(const float* __restrict__ comb,
                                              const float* __restrict__ fw,
                                              const float* __restrict__ al,
                                              const float* __restrict__ ar,
                                              float* __restrict__ feat,
                                              float* __restrict__ el,
                                              float* __restrict__ er) {
    const int BN = 16;
    int t = threadIdx.x;
    int n0 = blockIdx.x * BN;
    const float* cb = comb + (size_t)n0 * 256;
    float acc[BN];
#pragma unroll
    for (int n = 0; n < BN; ++n) acc[n] = 0.f;
    for (int k = 0; k < 256; k += 4) {
        float w0 = fw[(k + 0) * 256 + t];
        float w1 = fw[(k + 1) * 256 + t];
        float w2 = fw[(k + 2) * 256 + t];
        float w3 = fw[(k + 3) * 256 + t];
#pragma unroll
        for (int n = 0; n < BN; ++n) {
            acc[n] += cb[n * 256 + k + 0] * w0 + cb[n * 256 + k + 1] * w1 +
                      cb[n * 256 + k + 2] * w2 + cb[n * 256 + k + 3] * w3;
        }
    }
    float a_l = al[t], a_r = ar[t];
    int lane = t & 63, head = t >> 6;
#pragma unroll
    for (int n = 0; n < BN; ++n) {
        feat[(size_t)(n0 + n) * 256 + t] = acc[n];
        float xl = acc[n] * a_l, xr = acc[n] * a_r;
#pragma unroll
        for (int off = 32; off > 0; off >>= 1) {
            xl += __shfl_xor(xl, off, 64);
            xr += __shfl_xor(xr, off, 64);
        }
        if (lane == 0) {
            el[(n0 + n) * 4 + head] = xl;
            er[(n0 + n) * 4 + head] = xr;
        }
    }
}

// ---------------- edge attention: exp(leaky_relu(el[src]+er[dst])), denom scatter ----
// NOTE: max-subtraction dropped intentionally — logits are O(1), exp is safe in f32
// and the softmax ratio is mathematically identical.
__global__ void k_edge_attn(const int* __restrict__ src, const int* __restrict__ dst,
                            const float* __restrict__ el, const float* __restrict__ er,
                            float* __restrict__ exs, float* __restrict__ denom) {
    int tid = blockIdx.x * 256 + threadIdx.x;
    if (tid >= N_EDGES * 4) return;
    int e = tid >> 2, hh = tid & 3;
    float v = el[src[e] * 4 + hh] + er[dst[e] * 4 + hh];
    v = v > 0.f ? v : 0.01f * v;
    float ex = __expf(v);
    exs[tid] = ex;
    atomicAdd(&denom[dst[e] * 4 + hh], ex);
}

// ---------------- message scatter: out[dst] += feat[src] * a ----------------
__global__ void k_scatter(const int* __restrict__ src, const int* __restrict__ dst,
                          const float* __restrict__ feat, const float* __restrict__ exs,
                          const float* __restrict__ denom, float* __restrict__ out) {
    int e = blockIdx.x;
    int t = threadIdx.x;
    int s = src[e], d = dst[e];
    int hh = t >> 6;
    float a = exs[e * 4 + hh] / fmaxf(denom[d * 4 + hh], 1e-16f);
    atomicAdd(&out[(size_t)d * 256 + t], feat[(size_t)s * 256 + t] * a);
}

// ---------------- in-place ELU ----------------
__global__ void k_elu(float* __restrict__ out) {
    int i = blockIdx.x * 256 + threadIdx.x;
    float x = out[i];
    out[i] = x > 0.f ? x : expm1f(x);
}

extern "C" void kernel_launch(void* const* d_in, const int* in_sizes, int n_in,
                              void* d_out, int out_size, void* d_ws, size_t ws_size,
                              hipStream_t stream) {
    const float* h      = (const float*)d_in[0];
    const float* time_t = (const float*)d_in[1];
    const int*   src    = (const int*)d_in[2];
    const int*   dst    = (const int*)d_in[3];
    const float* tw     = (const float*)d_in[4];
    const float* tb     = (const float*)d_in[5];
    const float* fw     = (const float*)d_in[6];
    const float* al     = (const float*)d_in[7];
    const float* ar     = (const float*)d_in[8];
    float* out = (float*)d_out;

    float* ws    = (float*)d_ws;
    float* agg   = ws;                          // N*64   (zeroed)
    float* deg   = agg + (size_t)N_NODES * 64;  // N      (zeroed)
    float* denom = deg + N_NODES;               // N*4    (zeroed)
    float* feat  = denom + (size_t)N_NODES * 4; // N*256
    float* el    = feat + (size_t)N_NODES * 256;// N*4
    float* er    = el + (size_t)N_NODES * 4;    // N*4
    float* exs   = agg;                         // E*4 aliases agg (agg dead after k_combine)

    size_t zero_bytes = (size_t)(N_NODES * 64 + N_NODES + N_NODES * 4) * sizeof(float);
    hipMemsetAsync(d_ws, 0, zero_bytes, stream);

    k_edge_time<<<(N_EDGES + 63) / 64, 256, 0, stream>>>(time_t, dst, tw, tb, agg, deg);
    k_combine<<<N_NODES, 256, 0, stream>>>(h, agg, deg, out);
    k_gemm<<<N_NODES / 16, 256, 0, stream>>>(out, fw, al, ar, feat, el, er);
    k_edge_attn<<<(N_EDGES * 4 + 255) / 256, 256, 0, stream>>>(src, dst, el, er, exs, denom);
    k_scatter<<<N_EDGES, 256, 0, stream>>>(src, dst, feat, exs, denom, out);
    k_elu<<<N_NODES, 256, 0, stream>>>(out);
}

// Round 2
// 494.141 us; speedup vs baseline: 1.4051x; 1.4051x over previous
//
#include <hip/hip_runtime.h>
#include <math.h>

#define N_NODES 50000
#define N_EDGES 400000
#define IN_DIM 192
#define TIME_DIM 64
#define GAT_IN 256
#define OUT_DIM 256

// ---------------- CSR build: histogram ----------------
__global__ void k_hist(const int* __restrict__ dst, int* __restrict__ deg) {
    int e = blockIdx.x * 256 + threadIdx.x;
    if (e >= N_EDGES) return;
    atomicAdd(&deg[dst[e]], 1);
}

// ---------------- CSR build: single-block chunked exclusive scan ----------------
// 1024 threads, each owns a 49-element chunk of deg[50000].
__global__ __launch_bounds__(1024) void k_scan(const int* __restrict__ deg,
                                               int* __restrict__ row_ptr,
                                               int* __restrict__ cursor) {
    __shared__ int part[1024];
    const int CH = 49; // 49*1024 = 50176 >= 50000
    int t = threadIdx.x;
    int base = t * CH;
    int s = 0;
    for (int j = 0; j < CH; ++j) {
        int i = base + j;
        if (i < N_NODES) s += deg[i];
    }
    part[t] = s;
    __syncthreads();
    // Hillis-Steele inclusive scan
    for (int off = 1; off < 1024; off <<= 1) {
        int v = (t >= off) ? part[t - off] : 0;
        __syncthreads();
        part[t] += v;
        __syncthreads();
    }
    int running = (t == 0) ? 0 : part[t - 1];
    for (int j = 0; j < CH; ++j) {
        int i = base + j;
        if (i < N_NODES) {
            row_ptr[i] = running;
            cursor[i] = running;
            running += deg[i];
        }
    }
    if (t == 1023) row_ptr[N_NODES] = part[1023];
}

// ---------------- CSR build: bucket edges by dst ----------------
__global__ void k_bucket(const int* __restrict__ src, const int* __restrict__ dst,
                         const float* __restrict__ time_t, int* __restrict__ cursor,
                         int* __restrict__ csr_src, float* __restrict__ csr_time) {
    int e = blockIdx.x * 256 + threadIdx.x;
    if (e >= N_EDGES) return;
    int d = dst[e];
    int idx = atomicAdd(&cursor[d], 1);
    csr_src[idx] = src[e];
    csr_time[idx] = time_t[e];
}

// ---------------- pass A: per-node time agg -> combined (in d_out) ----------------
// one wave per node; lane = time dim.
__global__ void k_node_time(const float* __restrict__ h, const float* __restrict__ csr_time,
                            const int* __restrict__ row_ptr,
                            const float* __restrict__ tw, const float* __restrict__ tb,
                            float* __restrict__ out) {
    int lane = threadIdx.x & 63;
    int wave = threadIdx.x >> 6;
    int d = blockIdx.x * 4 + wave;
    if (d >= N_NODES) return;
    int k0 = row_ptr[d], k1 = row_ptr[d + 1];
    float w = tw[lane], b = tb[lane];
    float s = 0.f;
    for (int k = k0; k < k1; ++k) {
        float t = csr_time[k];
        s += __cosf(t * w + b);
    }
    float mean = s / fmaxf((float)(k1 - k0), 1.0f);
    // write combined row: [h(192) | mean(64)]
    const float* hr = h + (size_t)d * IN_DIM;
    float* orow = out + (size_t)d * 256;
    orow[lane] = hr[lane];
    orow[lane + 64] = hr[lane + 64];
    orow[lane + 128] = hr[lane + 128];
    orow[lane + 192] = mean;
}

// ---------------- feat = combined @ fc_w ; el/er fused wave reductions ----------------
__global__ __launch_bounds__(256) void k_gemm(const float* __restrict__ comb,
                                              const float* __restrict__ fw,
                                              const float* __restrict__ al,
                                              const float* __restrict__ ar,
                                              float* __restrict__ feat,
                                              float* __restrict__ el,
                                              float* __restrict__ er) {
    const int BN = 16;
    int t = threadIdx.x;
    int n0 = blockIdx.x * BN;
    const float* cb = comb + (size_t)n0 * 256;
    float acc[BN];
#pragma unroll
    for (int n = 0; n < BN; ++n) acc[n] = 0.f;
    for (int k = 0; k < 256; k += 4) {
        float w0 = fw[(k + 0) * 256 + t];
        float w1 = fw[(k + 1) * 256 + t];
        float w2 = fw[(k + 2) * 256 + t];
        float w3 = fw[(k + 3) * 256 + t];
#pragma unroll
        for (int n = 0; n < BN; ++n) {
            acc[n] += cb[n * 256 + k + 0] * w0 + cb[n * 256 + k + 1] * w1 +
                      cb[n * 256 + k + 2] * w2 + cb[n * 256 + k + 3] * w3;
        }
    }
    float a_l = al[t], a_r = ar[t];
    int lane = t & 63, head = t >> 6;
#pragma unroll
    for (int n = 0; n < BN; ++n) {
        feat[(size_t)(n0 + n) * 256 + t] = acc[n];
        float xl = acc[n] * a_l, xr = acc[n] * a_r;
#pragma unroll
        for (int off = 32; off > 0; off >>= 1) {
            xl += __shfl_xor(xl, off, 64);
            xr += __shfl_xor(xr, off, 64);
        }
        if (lane == 0) {
            el[(n0 + n) * 4 + head] = xl;
            er[(n0 + n) * 4 + head] = xr;
        }
    }
}

// ---------------- pass B: fused edge-softmax + message agg + residual + ELU ----------
// one block (256 threads) per dst node; thread t owns output dim t.
// No max-subtraction: logits are O(1), softmax ratio identical in f32.
__global__ __launch_bounds__(256) void k_node_agg(const int* __restrict__ csr_src,
                                                  const int* __restrict__ row_ptr,
                                                  const float* __restrict__ feat,
                                                  const float* __restrict__ el,
                                                  const float* __restrict__ er,
                                                  float* __restrict__ out) {
    int d = blockIdx.x;
    int t = threadIdx.x;
    int hh = t >> 6;
    int k0 = row_ptr[d], k1 = row_ptr[d + 1];
    float er_d = er[d * 4 + hh];
    float acc = 0.f, den = 0.f;
    for (int k = k0; k < k1; ++k) {
        int s = csr_src[k];
        float v = el[s * 4 + hh] + er_d;
        v = v > 0.f ? v : 0.01f * v;
        float ex = __expf(v);
        den += ex;
        acc += feat[(size_t)s * 256 + t] * ex;
    }
    float* orow = out + (size_t)d * 256;
    float x = orow[t] + acc / fmaxf(den, 1e-16f);
    orow[t] = x > 0.f ? x : expm1f(x);
}

extern "C" void kernel_launch(void* const* d_in, const int* in_sizes, int n_in,
                              void* d_out, int out_size, void* d_ws, size_t ws_size,
                              hipStream_t stream) {
    const float* h      = (const float*)d_in[0];
    const float* time_t = (const float*)d_in[1];
    const int*   src    = (const int*)d_in[2];
    const int*   dst    = (const int*)d_in[3];
    const float* tw     = (const float*)d_in[4];
    const float* tb     = (const float*)d_in[5];
    const float* fw     = (const float*)d_in[6];
    const float* al     = (const float*)d_in[7];
    const float* ar     = (const float*)d_in[8];
    float* out = (float*)d_out;

    // workspace layout
    int*   deg      = (int*)d_ws;                       // N (zeroed)
    int*   row_ptr  = deg + N_NODES;                    // N+1
    int*   cursor   = row_ptr + N_NODES + 1;            // N
    int*   csr_src  = cursor + N_NODES;                 // E
    float* csr_time = (float*)(csr_src + N_EDGES);      // E
    float* feat     = csr_time + N_EDGES;               // N*256
    float* el       = feat + (size_t)N_NODES * 256;     // N*4
    float* er       = el + (size_t)N_NODES * 4;         // N*4

    hipMemsetAsync(deg, 0, N_NODES * sizeof(int), stream);

    k_hist<<<(N_EDGES + 255) / 256, 256, 0, stream>>>(dst, deg);
    k_scan<<<1, 1024, 0, stream>>>(deg, row_ptr, cursor);
    k_bucket<<<(N_EDGES + 255) / 256, 256, 0, stream>>>(src, dst, time_t, cursor, csr_src, csr_time);
    k_node_time<<<(N_NODES + 3) / 4, 256, 0, stream>>>(h, csr_time, row_ptr, tw, tb, out);
    k_gemm<<<N_NODES / 16, 256, 0, stream>>>(out, fw, al, ar, feat, el, er);
    k_node_agg<<<N_NODES, 256, 0, stream>>>(csr_src, row_ptr, feat, el, er, out);
}

// Round 3
// 365.284 us; speedup vs baseline: 1.9007x; 1.3528x over previous
//
#include <hip/hip_runtime.h>
#include <hip/hip_bf16.h>
#include <math.h>

#define N_NODES 50000
#define NP      50048   // padded to 64-row multiple for the MFMA grid
#define N_EDGES 400000
#define IN_DIM  192

typedef float        f32x4 __attribute__((ext_vector_type(4)));
typedef unsigned int u32x4 __attribute__((ext_vector_type(4)));

__device__ __forceinline__ unsigned short f2bf(float f) {
    union { float f; unsigned int u; } v; v.f = f;
    unsigned int r = (v.u + 0x7FFF + ((v.u >> 16) & 1)) >> 16; // RNE
    return (unsigned short)r;
}
__device__ __forceinline__ float bf2f(unsigned short u) {
    union { unsigned int u; float f; } v; v.u = ((unsigned int)u) << 16;
    return v.f;
}

// D(16x16) += A(16x32,bf16) * B(32x16,bf16); a/b = 8 bf16 per lane (4 VGPRs).
// A row / B col = lane&15; k-slot packing consistent between A and B (8 contiguous
// k per lane at k = 8*(lane>>4)+j) -> correct by slot-pairing invariance.
#define MFMA_BF16(acc, a, b) \
    asm("v_mfma_f32_16x16x32_bf16 %0, %1, %2, %0" : "+v"(acc) : "v"(a), "v"(b))

// ---------------- CSR build ----------------
__global__ void k_hist(const int* __restrict__ dst, int* __restrict__ deg) {
    int e = blockIdx.x * 256 + threadIdx.x;
    if (e >= N_EDGES) return;
    atomicAdd(&deg[dst[e]], 1);
}

__global__ __launch_bounds__(1024) void k_scan(const int* __restrict__ deg,
                                               int* __restrict__ row_ptr,
                                               int* __restrict__ cursor) {
    __shared__ int part[1024];
    const int CH = 49; // 49*1024 = 50176 >= 50000
    int t = threadIdx.x;
    int base = t * CH;
    int s = 0;
    for (int j = 0; j < CH; ++j) {
        int i = base + j;
        if (i < N_NODES) s += deg[i];
    }
    part[t] = s;
    __syncthreads();
    for (int off = 1; off < 1024; off <<= 1) {
        int v = (t >= off) ? part[t - off] : 0;
        __syncthreads();
        part[t] += v;
        __syncthreads();
    }
    int running = (t == 0) ? 0 : part[t - 1];
    for (int j = 0; j < CH; ++j) {
        int i = base + j;
        if (i < N_NODES) {
            row_ptr[i] = running;
            cursor[i] = running;
            running += deg[i];
        }
    }
    if (t == 1023) row_ptr[N_NODES] = part[1023];
}

__global__ void k_bucket(const int* __restrict__ src, const int* __restrict__ dst,
                         const float* __restrict__ time_t, int* __restrict__ cursor,
                         int* __restrict__ csr_src, float* __restrict__ csr_time) {
    int e = blockIdx.x * 256 + threadIdx.x;
    if (e >= N_EDGES) return;
    int d = dst[e];
    int idx = atomicAdd(&cursor[d], 1);
    csr_src[idx] = src[e];
    csr_time[idx] = time_t[e];
}

// ---------------- fc_w -> bf16 W^T [n][k] ----------------
__global__ void k_prep_w(const float* __restrict__ fw, unsigned short* __restrict__ wT) {
    int n = blockIdx.x;
    int k = threadIdx.x;
    wT[n * 256 + k] = f2bf(fw[k * 256 + n]);
}

// ---------------- per-node time agg -> combined bf16 [NP][256] ----------------
__global__ void k_node_time(const float* __restrict__ h, const float* __restrict__ csr_time,
                            const int* __restrict__ row_ptr,
                            const float* __restrict__ tw, const float* __restrict__ tb,
                            unsigned short* __restrict__ comb) {
    int lane = threadIdx.x & 63;
    int d = blockIdx.x * 4 + (threadIdx.x >> 6);
    if (d >= N_NODES) return;
    int k0 = row_ptr[d], k1 = row_ptr[d + 1];
    float w = tw[lane], b = tb[lane];
    float s = 0.f;
    for (int k = k0; k < k1; ++k) s += __cosf(csr_time[k] * w + b);
    float mean = s / fmaxf((float)(k1 - k0), 1.0f);
    const float* hr = h + (size_t)d * IN_DIM;
    unsigned short* orow = comb + (size_t)d * 256;
    orow[lane]       = f2bf(hr[lane]);
    orow[lane + 64]  = f2bf(hr[lane + 64]);
    orow[lane + 128] = f2bf(hr[lane + 128]);
    orow[lane + 192] = f2bf(mean);
}

// ---------------- MFMA GEMM: feat = combined @ fc_w ; fused el/er ----------------
// 4 waves/block; wave computes 16 rows x 256 cols. K=256 in 8 steps of 32.
__global__ __launch_bounds__(256) void k_gemm_mfma(
        const unsigned short* __restrict__ comb,  // [NP][256] bf16
        const unsigned short* __restrict__ wT,    // [256][256] bf16, [n][k]
        const float* __restrict__ al, const float* __restrict__ ar,
        unsigned short* __restrict__ feat,        // [NP][256] bf16
        float* __restrict__ el, float* __restrict__ er) {
    int lane = threadIdx.x & 63;
    int wave = threadIdx.x >> 6;
    int r0 = blockIdx.x * 64 + wave * 16;
    int c = lane & 15;     // A row / B col within tile
    int g = lane >> 4;     // k-slot group

    f32x4 acc[16];
#pragma unroll
    for (int nt = 0; nt < 16; ++nt) acc[nt] = (f32x4){0.f, 0.f, 0.f, 0.f};

    const unsigned short* arow = comb + (size_t)(r0 + c) * 256 + g * 8;
    const unsigned short* brow = wT + (size_t)c * 256 + g * 8;

    for (int ks = 0; ks < 8; ++ks) {
        u32x4 a = *(const u32x4*)(arow + ks * 32);
#pragma unroll
        for (int nt = 0; nt < 16; ++nt) {
            u32x4 b = *(const u32x4*)(brow + nt * 4096 + ks * 32);
            MFMA_BF16(acc[nt], a, b);
        }
    }

    int row_lo = r0 + g * 4;  // this lane holds rows row_lo..row_lo+3 (reg idx)
    // feat (bf16) store
#pragma unroll
    for (int nt = 0; nt < 16; ++nt) {
#pragma unroll
        for (int reg = 0; reg < 4; ++reg) {
            feat[(size_t)(row_lo + reg) * 256 + nt * 16 + c] = f2bf(acc[nt][reg]);
        }
    }
    // el/er: per head, weighted col-sum via 16-lane butterfly
#pragma unroll
    for (int hh = 0; hh < 4; ++hh) {
        float xl[4] = {0.f, 0.f, 0.f, 0.f};
        float xr[4] = {0.f, 0.f, 0.f, 0.f};
#pragma unroll
        for (int ntl = 0; ntl < 4; ++ntl) {
            int nt = hh * 4 + ntl;
            float av = al[nt * 16 + c];
            float rv = ar[nt * 16 + c];
#pragma unroll
            for (int reg = 0; reg < 4; ++reg) {
                xl[reg] += acc[nt][reg] * av;
                xr[reg] += acc[nt][reg] * rv;
            }
        }
#pragma unroll
        for (int reg = 0; reg < 4; ++reg) {
#pragma unroll
            for (int off = 1; off < 16; off <<= 1) {
                xl[reg] += __shfl_xor(xl[reg], off, 64);
                xr[reg] += __shfl_xor(xr[reg], off, 64);
            }
        }
        if (c == 0) {
#pragma unroll
            for (int reg = 0; reg < 4; ++reg) {
                el[(row_lo + reg) * 4 + hh] = xl[reg];
                er[(row_lo + reg) * 4 + hh] = xr[reg];
            }
        }
    }
}

// ---------------- fused edge-softmax + message agg + residual + ELU ----------------
// 2 nodes per 256-thread block; 128 threads per node, 2 cols each (bf16x2 loads).
__global__ __launch_bounds__(256) void k_node_agg(
        const int* __restrict__ csr_src, const int* __restrict__ row_ptr,
        const unsigned short* __restrict__ feat, const unsigned short* __restrict__ comb,
        const float* __restrict__ el, const float* __restrict__ er,
        float* __restrict__ out) {
    int local = threadIdx.x & 127;
    int d = blockIdx.x * 2 + (threadIdx.x >> 7);
    int c0 = local * 2;
    int hh = local >> 5;
    float er_d = er[d * 4 + hh];
    int k0 = row_ptr[d], k1 = row_ptr[d + 1];
    float a0 = 0.f, a1 = 0.f, den = 0.f;
    for (int k = k0; k < k1; ++k) {
        int s = csr_src[k];
        float v = el[s * 4 + hh] + er_d;
        v = v > 0.f ? v : 0.01f * v;
        float ex = __expf(v);
        den += ex;
        unsigned int f2 = *(const unsigned int*)&feat[(size_t)s * 256 + c0];
        a0 += bf2f((unsigned short)(f2 & 0xFFFF)) * ex;
        a1 += bf2f((unsigned short)(f2 >> 16)) * ex;
    }
    float inv = 1.0f / fmaxf(den, 1e-16f);
    unsigned int cb = *(const unsigned int*)&comb[(size_t)d * 256 + c0];
    float x0 = bf2f((unsigned short)(cb & 0xFFFF)) + a0 * inv;
    float x1 = bf2f((unsigned short)(cb >> 16)) + a1 * inv;
    float2 o;
    o.x = x0 > 0.f ? x0 : expm1f(x0);
    o.y = x1 > 0.f ? x1 : expm1f(x1);
    *(float2*)&out[(size_t)d * 256 + c0] = o;
}

extern "C" void kernel_launch(void* const* d_in, const int* in_sizes, int n_in,
                              void* d_out, int out_size, void* d_ws, size_t ws_size,
                              hipStream_t stream) {
    const float* h      = (const float*)d_in[0];
    const float* time_t = (const float*)d_in[1];
    const int*   src    = (const int*)d_in[2];
    const int*   dst    = (const int*)d_in[3];
    const float* tw     = (const float*)d_in[4];
    const float* tb     = (const float*)d_in[5];
    const float* fw     = (const float*)d_in[6];
    const float* al     = (const float*)d_in[7];
    const float* ar     = (const float*)d_in[8];
    float* out = (float*)d_out;

    // workspace layout (all segments 64B-aligned)
    char* p = (char*)d_ws;
    int*   deg      = (int*)p;                 p += 200000;          // N ints (zeroed)
    int*   row_ptr  = (int*)p;                 p += 200064;          // N+1 ints
    int*   cursor   = (int*)p;                                      // N ints
    unsigned short* wT = (unsigned short*)p;   p += 200000;          // wT aliases cursor (dead after bucket)
    int*   csr_src  = (int*)p;                 p += 1600000;         // E ints
    float* csr_time = (float*)p;               p += 1600000;         // E f32
    unsigned short* comb_bf = (unsigned short*)p; p += (size_t)NP * 512; // [NP][256] bf16
    unsigned short* feat_bf = (unsigned short*)p; p += (size_t)NP * 512; // [NP][256] bf16
    float* el       = (float*)p;               p += (size_t)NP * 16; // [NP][4]
    float* er       = (float*)p;               p += (size_t)NP * 16; // [NP][4]

    hipMemsetAsync(deg, 0, N_NODES * sizeof(int), stream);

    k_hist<<<(N_EDGES + 255) / 256, 256, 0, stream>>>(dst, deg);
    k_scan<<<1, 1024, 0, stream>>>(deg, row_ptr, cursor);
    k_bucket<<<(N_EDGES + 255) / 256, 256, 0, stream>>>(src, dst, time_t, cursor, csr_src, csr_time);
    k_prep_w<<<256, 256, 0, stream>>>(fw, wT);
    k_node_time<<<(N_NODES + 3) / 4, 256, 0, stream>>>(h, csr_time, row_ptr, tw, tb, comb_bf);
    k_gemm_mfma<<<NP / 64, 256, 0, stream>>>(comb_bf, wT, al, ar, feat_bf, el, er);
    k_node_agg<<<N_NODES / 2, 256, 0, stream>>>(csr_src, row_ptr, feat_bf, comb_bf, el, er, out);
}

// Round 4
// 249.975 us; speedup vs baseline: 2.7775x; 1.4613x over previous
//
#include <hip/hip_runtime.h>
#include <hip/hip_bf16.h>
#include <math.h>

#define N_NODES 50000
#define NP      50048   // padded to 64-row multiple for the MFMA grid
#define N_EDGES 400000
#define IN_DIM  192
#define NB      196     // scan blocks: 196*256 = 50176 >= 50000

typedef float        f32x4 __attribute__((ext_vector_type(4)));
typedef unsigned int u32x4 __attribute__((ext_vector_type(4)));

__device__ __forceinline__ unsigned short f2bf(float f) {
    union { float f; unsigned int u; } v; v.f = f;
    unsigned int r = (v.u + 0x7FFF + ((v.u >> 16) & 1)) >> 16; // RNE
    return (unsigned short)r;
}
__device__ __forceinline__ float bf2f(unsigned short u) {
    union { unsigned int u; float f; } v; v.u = ((unsigned int)u) << 16;
    return v.f;
}

// D(16x16) += A(16x32,bf16) * B(32x16,bf16); a/b = 8 bf16 per lane (4 VGPRs).
// k-slot packing consistent between A and B -> correct by slot-pairing invariance.
#define MFMA_BF16(acc, a, b) \
    asm("v_mfma_f32_16x16x32_bf16 %0, %1, %2, %0" : "+v"(acc) : "v"(a), "v"(b))

// ---------------- CSR build ----------------
__global__ void k_hist(const int* __restrict__ dst, int* __restrict__ deg) {
    int e = blockIdx.x * 256 + threadIdx.x;
    if (e >= N_EDGES) return;
    atomicAdd(&deg[dst[e]], 1);
}

// step 1: per-block sums of deg
__global__ __launch_bounds__(256) void k_blocksum(const int* __restrict__ deg,
                                                  int* __restrict__ bsum) {
    int i = blockIdx.x * 256 + threadIdx.x;
    int v = (i < N_NODES) ? deg[i] : 0;
#pragma unroll
    for (int off = 32; off > 0; off >>= 1) v += __shfl_down(v, off, 64);
    __shared__ int ws[4];
    if ((threadIdx.x & 63) == 0) ws[threadIdx.x >> 6] = v;
    __syncthreads();
    if (threadIdx.x == 0) bsum[blockIdx.x] = ws[0] + ws[1] + ws[2] + ws[3];
}

// step 2: scan the 196 block sums (one small block)
__global__ __launch_bounds__(256) void k_bsum_scan(const int* __restrict__ bsum,
                                                   int* __restrict__ boff,
                                                   int* __restrict__ row_ptr) {
    __shared__ int part[256];
    int t = threadIdx.x;
    int v = (t < NB) ? bsum[t] : 0;
    part[t] = v;
    __syncthreads();
#pragma unroll
    for (int off = 1; off < 256; off <<= 1) {
        int u = (t >= off) ? part[t - off] : 0;
        __syncthreads();
        part[t] += u;
        __syncthreads();
    }
    if (t < NB) boff[t] = part[t] - v;       // exclusive block offset
    if (t == 255) row_ptr[N_NODES] = part[255];
}

// step 3: local exclusive scan + block offset -> row_ptr, cursor
__global__ __launch_bounds__(256) void k_apply(const int* __restrict__ deg,
                                               const int* __restrict__ boff,
                                               int* __restrict__ row_ptr,
                                               int* __restrict__ cursor) {
    __shared__ int part[256];
    int t = threadIdx.x;
    int i = blockIdx.x * 256 + t;
    int v = (i < N_NODES) ? deg[i] : 0;
    part[t] = v;
    __syncthreads();
#pragma unroll
    for (int off = 1; off < 256; off <<= 1) {
        int u = (t >= off) ? part[t - off] : 0;
        __syncthreads();
        part[t] += u;
        __syncthreads();
    }
    if (i < N_NODES) {
        int ex = boff[blockIdx.x] + part[t] - v;
        row_ptr[i] = ex;
        cursor[i] = ex;
    }
}

__global__ void k_bucket(const int* __restrict__ src, const int* __restrict__ dst,
                         const float* __restrict__ time_t, int* __restrict__ cursor,
                         int* __restrict__ csr_src, float* __restrict__ csr_time) {
    int e = blockIdx.x * 256 + threadIdx.x;
    if (e >= N_EDGES) return;
    int d = dst[e];
    int idx = atomicAdd(&cursor[d], 1);
    csr_src[idx] = src[e];
    csr_time[idx] = time_t[e];
}

// ---------------- fc_w -> bf16 W^T [n][k] ----------------
__global__ void k_prep_w(const float* __restrict__ fw, unsigned short* __restrict__ wT) {
    int n = blockIdx.x;
    int k = threadIdx.x;
    wT[n * 256 + k] = f2bf(fw[k * 256 + n]);
}

// ---------------- per-node time agg -> combined bf16 [NP][256] ----------------
__global__ void k_node_time(const float* __restrict__ h, const float* __restrict__ csr_time,
                            const int* __restrict__ row_ptr,
                            const float* __restrict__ tw, const float* __restrict__ tb,
                            unsigned short* __restrict__ comb) {
    int lane = threadIdx.x & 63;
    int d = blockIdx.x * 4 + (threadIdx.x >> 6);
    if (d >= N_NODES) return;
    int k0 = row_ptr[d], k1 = row_ptr[d + 1];
    float w = tw[lane], b = tb[lane];
    float s = 0.f;
    for (int k = k0; k < k1; ++k) s += __cosf(csr_time[k] * w + b);
    float mean = s / fmaxf((float)(k1 - k0), 1.0f);
    const float* hr = h + (size_t)d * IN_DIM;
    unsigned short* orow = comb + (size_t)d * 256;
    orow[lane]       = f2bf(hr[lane]);
    orow[lane + 64]  = f2bf(hr[lane + 64]);
    orow[lane + 128] = f2bf(hr[lane + 128]);
    orow[lane + 192] = f2bf(mean);
}

// ---------------- MFMA GEMM: feat = combined @ fc_w ; fused el/er ----------------
__global__ __launch_bounds__(256) void k_gemm_mfma(
        const unsigned short* __restrict__ comb,  // [NP][256] bf16
        const unsigned short* __restrict__ wT,    // [256][256] bf16, [n][k]
        const float* __restrict__ al, const float* __restrict__ ar,
        unsigned short* __restrict__ feat,        // [NP][256] bf16
        float* __restrict__ el, float* __restrict__ er) {
    int lane = threadIdx.x & 63;
    int wave = threadIdx.x >> 6;
    int r0 = blockIdx.x * 64 + wave * 16;
    int c = lane & 15;     // A row / B col within tile
    int g = lane >> 4;     // k-slot group

    f32x4 acc[16];
#pragma unroll
    for (int nt = 0; nt < 16; ++nt) acc[nt] = (f32x4){0.f, 0.f, 0.f, 0.f};

    const unsigned short* arow = comb + (size_t)(r0 + c) * 256 + g * 8;
    const unsigned short* brow = wT + (size_t)c * 256 + g * 8;

    for (int ks = 0; ks < 8; ++ks) {
        u32x4 a = *(const u32x4*)(arow + ks * 32);
#pragma unroll
        for (int nt = 0; nt < 16; ++nt) {
            u32x4 b = *(const u32x4*)(brow + nt * 4096 + ks * 32);
            MFMA_BF16(acc[nt], a, b);
        }
    }

    int row_lo = r0 + g * 4;  // this lane holds rows row_lo..row_lo+3 (reg idx)
#pragma unroll
    for (int nt = 0; nt < 16; ++nt) {
#pragma unroll
        for (int reg = 0; reg < 4; ++reg) {
            feat[(size_t)(row_lo + reg) * 256 + nt * 16 + c] = f2bf(acc[nt][reg]);
        }
    }
#pragma unroll
    for (int hh = 0; hh < 4; ++hh) {
        float xl[4] = {0.f, 0.f, 0.f, 0.f};
        float xr[4] = {0.f, 0.f, 0.f, 0.f};
#pragma unroll
        for (int ntl = 0; ntl < 4; ++ntl) {
            int nt = hh * 4 + ntl;
            float av = al[nt * 16 + c];
            float rv = ar[nt * 16 + c];
#pragma unroll
            for (int reg = 0; reg < 4; ++reg) {
                xl[reg] += acc[nt][reg] * av;
                xr[reg] += acc[nt][reg] * rv;
            }
        }
#pragma unroll
        for (int reg = 0; reg < 4; ++reg) {
#pragma unroll
            for (int off = 1; off < 16; off <<= 1) {
                xl[reg] += __shfl_xor(xl[reg], off, 64);
                xr[reg] += __shfl_xor(xr[reg], off, 64);
            }
        }
        if (c == 0) {
#pragma unroll
            for (int reg = 0; reg < 4; ++reg) {
                el[(row_lo + reg) * 4 + hh] = xl[reg];
                er[(row_lo + reg) * 4 + hh] = xr[reg];
            }
        }
    }
}

// ---------------- fused edge-softmax + message agg + residual + ELU ----------------
__global__ __launch_bounds__(256) void k_node_agg(
        const int* __restrict__ csr_src, const int* __restrict__ row_ptr,
        const unsigned short* __restrict__ feat, const unsigned short* __restrict__ comb,
        const float* __restrict__ el, const float* __restrict__ er,
        float* __restrict__ out) {
    int local = threadIdx.x & 127;
    int d = blockIdx.x * 2 + (threadIdx.x >> 7);
    int c0 = local * 2;
    int hh = local >> 5;
    float er_d = er[d * 4 + hh];
    int k0 = row_ptr[d], k1 = row_ptr[d + 1];
    float a0 = 0.f, a1 = 0.f, den = 0.f;
    for (int k = k0; k < k1; ++k) {
        int s = csr_src[k];
        float v = el[s * 4 + hh] + er_d;
        v = v > 0.f ? v : 0.01f * v;
        float ex = __expf(v);
        den += ex;
        unsigned int f2 = *(const unsigned int*)&feat[(size_t)s * 256 + c0];
        a0 += bf2f((unsigned short)(f2 & 0xFFFF)) * ex;
        a1 += bf2f((unsigned short)(f2 >> 16)) * ex;
    }
    float inv = 1.0f / fmaxf(den, 1e-16f);
    unsigned int cb = *(const unsigned int*)&comb[(size_t)d * 256 + c0];
    float x0 = bf2f((unsigned short)(cb & 0xFFFF)) + a0 * inv;
    float x1 = bf2f((unsigned short)(cb >> 16)) + a1 * inv;
    float2 o;
    o.x = x0 > 0.f ? x0 : expm1f(x0);
    o.y = x1 > 0.f ? x1 : expm1f(x1);
    *(float2*)&out[(size_t)d * 256 + c0] = o;
}

extern "C" void kernel_launch(void* const* d_in, const int* in_sizes, int n_in,
                              void* d_out, int out_size, void* d_ws, size_t ws_size,
                              hipStream_t stream) {
    const float* h      = (const float*)d_in[0];
    const float* time_t = (const float*)d_in[1];
    const int*   src    = (const int*)d_in[2];
    const int*   dst    = (const int*)d_in[3];
    const float* tw     = (const float*)d_in[4];
    const float* tb     = (const float*)d_in[5];
    const float* fw     = (const float*)d_in[6];
    const float* al     = (const float*)d_in[7];
    const float* ar     = (const float*)d_in[8];
    float* out = (float*)d_out;

    // workspace layout (all segments 64B-aligned)
    char* p = (char*)d_ws;
    int*   deg      = (int*)p;                 p += 200000;          // N ints (zeroed)
    int*   row_ptr  = (int*)p;                 p += 200064;          // N+1 ints
    int*   cursor   = (int*)p;                                      // N ints
    unsigned short* wT = (unsigned short*)p;   p += 200000;          // wT aliases cursor (dead after bucket)
    int*   csr_src  = (int*)p;                 p += 1600000;         // E ints
    float* csr_time = (float*)p;               p += 1600000;         // E f32
    unsigned short* comb_bf = (unsigned short*)p; p += (size_t)NP * 512; // [NP][256] bf16
    unsigned short* feat_bf = (unsigned short*)p; p += (size_t)NP * 512; // [NP][256] bf16
    float* el       = (float*)p;               p += (size_t)NP * 16; // [NP][4]
    float* er       = (float*)p;               p += (size_t)NP * 16; // [NP][4]
    int*   bsum     = (int*)p;                 p += 256 * 4;         // NB block sums
    int*   boff     = (int*)p;                 p += 256 * 4;         // NB block offsets

    hipMemsetAsync(deg, 0, N_NODES * sizeof(int), stream);

    k_hist<<<(N_EDGES + 255) / 256, 256, 0, stream>>>(dst, deg);
    k_blocksum<<<NB, 256, 0, stream>>>(deg, bsum);
    k_bsum_scan<<<1, 256, 0, stream>>>(bsum, boff, row_ptr);
    k_apply<<<NB, 256, 0, stream>>>(deg, boff, row_ptr, cursor);
    k_bucket<<<(N_EDGES + 255) / 256, 256, 0, stream>>>(src, dst, time_t, cursor, csr_src, csr_time);
    k_prep_w<<<256, 256, 0, stream>>>(fw, wT);
    k_node_time<<<(N_NODES + 3) / 4, 256, 0, stream>>>(h, csr_time, row_ptr, tw, tb, comb_bf);
    k_gemm_mfma<<<NP / 64, 256, 0, stream>>>(comb_bf, wT, al, ar, feat_bf, el, er);
    k_node_agg<<<N_NODES / 2, 256, 0, stream>>>(csr_src, row_ptr, feat_bf, comb_bf, el, er, out);
}

// Round 5
// 200.870 us; speedup vs baseline: 3.4565x; 1.2445x over previous
//
#include <hip/hip_runtime.h>
#include <hip/hip_bf16.h>
#include <math.h>

#define N_NODES 50000
#define NP      50048   // padded to 64-row multiple for the MFMA grid
#define N_EDGES 400000
#define IN_DIM  192
#define NB      196     // scan blocks: 196*256 = 50176 >= 50000

typedef float        f32x4 __attribute__((ext_vector_type(4)));
typedef unsigned int u32x4 __attribute__((ext_vector_type(4)));

__device__ __forceinline__ unsigned short f2bf(float f) {
    union { float f; unsigned int u; } v; v.f = f;
    unsigned int r = (v.u + 0x7FFF + ((v.u >> 16) & 1)) >> 16; // RNE
    return (unsigned short)r;
}
__device__ __forceinline__ float bf2f(unsigned short u) {
    union { unsigned int u; float f; } v; v.u = ((unsigned int)u) << 16;
    return v.f;
}
__device__ __forceinline__ float bfu_lo(unsigned int u) {
    union { unsigned int u; float f; } v; v.u = u << 16;
    return v.f;
}
__device__ __forceinline__ float bfu_hi(unsigned int u) {
    union { unsigned int u; float f; } v; v.u = u & 0xFFFF0000u;
    return v.f;
}

// D(16x16) += A(16x32,bf16) * B(32x16,bf16); a/b = 8 bf16 per lane (4 VGPRs).
// k-slot packing consistent between A and B -> correct by slot-pairing invariance.
#define MFMA_BF16(acc, a, b) \
    asm("v_mfma_f32_16x16x32_bf16 %0, %1, %2, %0" : "+v"(acc) : "v"(a), "v"(b))

// ---------------- CSR build ----------------
__global__ void k_hist(const int* __restrict__ dst, int* __restrict__ deg) {
    int e = blockIdx.x * 256 + threadIdx.x;
    if (e >= N_EDGES) return;
    atomicAdd(&deg[dst[e]], 1);
}

__global__ __launch_bounds__(256) void k_blocksum(const int* __restrict__ deg,
                                                  int* __restrict__ bsum) {
    int i = blockIdx.x * 256 + threadIdx.x;
    int v = (i < N_NODES) ? deg[i] : 0;
#pragma unroll
    for (int off = 32; off > 0; off >>= 1) v += __shfl_down(v, off, 64);
    __shared__ int ws[4];
    if ((threadIdx.x & 63) == 0) ws[threadIdx.x >> 6] = v;
    __syncthreads();
    if (threadIdx.x == 0) bsum[blockIdx.x] = ws[0] + ws[1] + ws[2] + ws[3];
}

__global__ __launch_bounds__(256) void k_bsum_scan(const int* __restrict__ bsum,
                                                   int* __restrict__ boff,
                                                   int* __restrict__ row_ptr) {
    __shared__ int part[256];
    int t = threadIdx.x;
    int v = (t < NB) ? bsum[t] : 0;
    part[t] = v;
    __syncthreads();
#pragma unroll
    for (int off = 1; off < 256; off <<= 1) {
        int u = (t >= off) ? part[t - off] : 0;
        __syncthreads();
        part[t] += u;
        __syncthreads();
    }
    if (t < NB) boff[t] = part[t] - v;       // exclusive block offset
    if (t == 255) row_ptr[N_NODES] = part[255];
}

__global__ __launch_bounds__(256) void k_apply(const int* __restrict__ deg,
                                               const int* __restrict__ boff,
                                               int* __restrict__ row_ptr,
                                               int* __restrict__ cursor) {
    __shared__ int part[256];
    int t = threadIdx.x;
    int i = blockIdx.x * 256 + t;
    int v = (i < N_NODES) ? deg[i] : 0;
    part[t] = v;
    __syncthreads();
#pragma unroll
    for (int off = 1; off < 256; off <<= 1) {
        int u = (t >= off) ? part[t - off] : 0;
        __syncthreads();
        part[t] += u;
        __syncthreads();
    }
    if (i < N_NODES) {
        int ex = boff[blockIdx.x] + part[t] - v;
        row_ptr[i] = ex;
        cursor[i] = ex;
    }
}

__global__ void k_bucket(const int* __restrict__ src, const int* __restrict__ dst,
                         const float* __restrict__ time_t, int* __restrict__ cursor,
                         int* __restrict__ csr_src, float* __restrict__ csr_time) {
    int e = blockIdx.x * 256 + threadIdx.x;
    if (e >= N_EDGES) return;
    int d = dst[e];
    int idx = atomicAdd(&cursor[d], 1);
    csr_src[idx] = src[e];
    csr_time[idx] = time_t[e];
}

// ---------------- fc_w -> bf16 W^T [n][k] ----------------
__global__ void k_prep_w(const float* __restrict__ fw, unsigned short* __restrict__ wT) {
    int n = blockIdx.x;
    int k = threadIdx.x;
    wT[n * 256 + k] = f2bf(fw[k * 256 + n]);
}

// ---------------- per-node time agg -> combined bf16 [NP][256] ----------------
__global__ void k_node_time(const float* __restrict__ h, const float* __restrict__ csr_time,
                            const int* __restrict__ row_ptr,
                            const float* __restrict__ tw, const float* __restrict__ tb,
                            unsigned short* __restrict__ comb) {
    int lane = threadIdx.x & 63;
    int d = blockIdx.x * 4 + (threadIdx.x >> 6);
    if (d >= N_NODES) return;
    int k0 = row_ptr[d], k1 = row_ptr[d + 1];
    float w = tw[lane], b = tb[lane];
    float s = 0.f;
    for (int k = k0; k < k1; ++k) s += __cosf(csr_time[k] * w + b);
    float mean = s / fmaxf((float)(k1 - k0), 1.0f);
    const float* hr = h + (size_t)d * IN_DIM;
    unsigned short* orow = comb + (size_t)d * 256;
    orow[lane]       = f2bf(hr[lane]);
    orow[lane + 64]  = f2bf(hr[lane + 64]);
    orow[lane + 128] = f2bf(hr[lane + 128]);
    orow[lane + 192] = f2bf(mean);
}

// ---------------- MFMA GEMM: feat = combined @ fc_w ; fused el/er ----------------
__global__ __launch_bounds__(256) void k_gemm_mfma(
        const unsigned short* __restrict__ comb,  // [NP][256] bf16
        const unsigned short* __restrict__ wT,    // [256][256] bf16, [n][k]
        const float* __restrict__ al, const float* __restrict__ ar,
        unsigned short* __restrict__ feat,        // [NP][256] bf16
        float* __restrict__ el, float* __restrict__ er) {
    int lane = threadIdx.x & 63;
    int wave = threadIdx.x >> 6;
    int r0 = blockIdx.x * 64 + wave * 16;
    int c = lane & 15;     // A row / B col within tile
    int g = lane >> 4;     // k-slot group

    f32x4 acc[16];
#pragma unroll
    for (int nt = 0; nt < 16; ++nt) acc[nt] = (f32x4){0.f, 0.f, 0.f, 0.f};

    const unsigned short* arow = comb + (size_t)(r0 + c) * 256 + g * 8;
    const unsigned short* brow = wT + (size_t)c * 256 + g * 8;

    for (int ks = 0; ks < 8; ++ks) {
        u32x4 a = *(const u32x4*)(arow + ks * 32);
#pragma unroll
        for (int nt = 0; nt < 16; ++nt) {
            u32x4 b = *(const u32x4*)(brow + nt * 4096 + ks * 32);
            MFMA_BF16(acc[nt], a, b);
        }
    }

    int row_lo = r0 + g * 4;  // this lane holds rows row_lo..row_lo+3 (reg idx)
#pragma unroll
    for (int nt = 0; nt < 16; ++nt) {
#pragma unroll
        for (int reg = 0; reg < 4; ++reg) {
            feat[(size_t)(row_lo + reg) * 256 + nt * 16 + c] = f2bf(acc[nt][reg]);
        }
    }
#pragma unroll
    for (int hh = 0; hh < 4; ++hh) {
        float xl[4] = {0.f, 0.f, 0.f, 0.f};
        float xr[4] = {0.f, 0.f, 0.f, 0.f};
#pragma unroll
        for (int ntl = 0; ntl < 4; ++ntl) {
            int nt = hh * 4 + ntl;
            float av = al[nt * 16 + c];
            float rv = ar[nt * 16 + c];
#pragma unroll
            for (int reg = 0; reg < 4; ++reg) {
                xl[reg] += acc[nt][reg] * av;
                xr[reg] += acc[nt][reg] * rv;
            }
        }
#pragma unroll
        for (int reg = 0; reg < 4; ++reg) {
#pragma unroll
            for (int off = 1; off < 16; off <<= 1) {
                xl[reg] += __shfl_xor(xl[reg], off, 64);
                xr[reg] += __shfl_xor(xr[reg], off, 64);
            }
        }
        if (c == 0) {
#pragma unroll
            for (int reg = 0; reg < 4; ++reg) {
                el[(row_lo + reg) * 4 + hh] = xl[reg];
                er[(row_lo + reg) * 4 + hh] = xr[reg];
            }
        }
    }
}

// ---------------- fused edge-softmax + message agg + residual + ELU ----------------
// Wave-synchronous: 1 wave = 1 node (4 nodes / 256-thread block).
// Phase A: lanes = (edge j, head h) compute exp ONCE per (edge,head) -> wave-private
//          LDS; per-lane den partials (normalization algebraically hoisted: acc/den
//          at the end, so chunks need no renormalize).
// Phase B: lane owns 4 cols; feat loaded as bf16x4 (8B); ex broadcast from LDS.
// No __syncthreads: LDS regions are wave-private; same-wave ds_write->ds_read is
// ordered by compiler-inserted lgkmcnt waits. No divergent-barrier hazard.
#define CHUNK 64
__global__ __launch_bounds__(256) void k_node_agg(
        const int* __restrict__ csr_src, const int* __restrict__ row_ptr,
        const unsigned short* __restrict__ feat, const unsigned short* __restrict__ comb,
        const float* __restrict__ el, const float* __restrict__ er,
        float* __restrict__ out) {
    __shared__ float ex_lds[4][CHUNK * 4];
    __shared__ int   src_lds[4][CHUNK];
    int lane = threadIdx.x & 63;
    int wv   = threadIdx.x >> 6;
    int d = blockIdx.x * 4 + wv;           // grid = N/4 exact
    int k0 = row_ptr[d], k1 = row_ptr[d + 1];
    int j4 = lane >> 2, h4 = lane & 3;     // phase A: lane -> (edge-slot, head)
    int hh = lane >> 4;                    // phase B: head of owned cols
    float er_a = er[d * 4 + h4];
    float acc0 = 0.f, acc1 = 0.f, acc2 = 0.f, acc3 = 0.f, den_part = 0.f;

    for (int kc = k0; kc < k1; kc += CHUNK) {
        int cd = min(CHUNK, k1 - kc);
        // ---- phase A: ex + src stash ----
        for (int p = 0; p * 16 < cd; ++p) {
            int j = p * 16 + j4;
            if (j < cd) {
                int s = csr_src[kc + j];
                if (h4 == 0) src_lds[wv][j] = s;
                float v = el[s * 4 + h4] + er_a;
                v = v > 0.f ? v : 0.01f * v;
                float exv = __expf(v);
                ex_lds[wv][j * 4 + h4] = exv;
                den_part += exv;
            }
        }
        // ---- phase B: weighted gather ----
#pragma unroll 2
        for (int j = 0; j < cd; ++j) {
            int s = src_lds[wv][j];
            float a = ex_lds[wv][j * 4 + hh];
            const uint2* fp = (const uint2*)(feat + (size_t)s * 256 + lane * 4);
            uint2 u = *fp;
            acc0 += bfu_lo(u.x) * a;
            acc1 += bfu_hi(u.x) * a;
            acc2 += bfu_lo(u.y) * a;
            acc3 += bfu_hi(u.y) * a;
        }
    }
    // den: butterfly over lanes sharing (lane&3), then fetch den[hh]
    float dred = den_part;
    dred += __shfl_xor(dred, 4, 64);
    dred += __shfl_xor(dred, 8, 64);
    dred += __shfl_xor(dred, 16, 64);
    dred += __shfl_xor(dred, 32, 64);     // lane m now holds den[m&3]
    float den = __shfl(dred, hh, 64);     // lane hh (0..3) holds den[hh]
    float inv = 1.0f / fmaxf(den, 1e-16f);

    uint2 cb = *(const uint2*)(comb + (size_t)d * 256 + lane * 4);
    float x0 = bfu_lo(cb.x) + acc0 * inv;
    float x1 = bfu_hi(cb.x) + acc1 * inv;
    float x2 = bfu_lo(cb.y) + acc2 * inv;
    float x3 = bfu_hi(cb.y) + acc3 * inv;
    float4 o;
    o.x = x0 > 0.f ? x0 : expm1f(x0);
    o.y = x1 > 0.f ? x1 : expm1f(x1);
    o.z = x2 > 0.f ? x2 : expm1f(x2);
    o.w = x3 > 0.f ? x3 : expm1f(x3);
    *(float4*)&out[(size_t)d * 256 + lane * 4] = o;
}

extern "C" void kernel_launch(void* const* d_in, const int* in_sizes, int n_in,
                              void* d_out, int out_size, void* d_ws, size_t ws_size,
                              hipStream_t stream) {
    const float* h      = (const float*)d_in[0];
    const float* time_t = (const float*)d_in[1];
    const int*   src    = (const int*)d_in[2];
    const int*   dst    = (const int*)d_in[3];
    const float* tw     = (const float*)d_in[4];
    const float* tb     = (const float*)d_in[5];
    const float* fw     = (const float*)d_in[6];
    const float* al     = (const float*)d_in[7];
    const float* ar     = (const float*)d_in[8];
    float* out = (float*)d_out;

    // workspace layout (all segments 64B-aligned)
    char* p = (char*)d_ws;
    int*   deg      = (int*)p;                 p += 200000;          // N ints (zeroed)
    int*   row_ptr  = (int*)p;                 p += 200064;          // N+1 ints
    int*   cursor   = (int*)p;                                      // N ints
    unsigned short* wT = (unsigned short*)p;   p += 200000;          // wT aliases cursor (dead after bucket)
    int*   csr_src  = (int*)p;                 p += 1600000;         // E ints
    float* csr_time = (float*)p;               p += 1600000;         // E f32
    unsigned short* comb_bf = (unsigned short*)p; p += (size_t)NP * 512; // [NP][256] bf16
    unsigned short* feat_bf = (unsigned short*)p; p += (size_t)NP * 512; // [NP][256] bf16
    float* el       = (float*)p;               p += (size_t)NP * 16; // [NP][4]
    float* er       = (float*)p;               p += (size_t)NP * 16; // [NP][4]
    int*   bsum     = (int*)p;                 p += 256 * 4;         // NB block sums
    int*   boff     = (int*)p;                 p += 256 * 4;         // NB block offsets

    hipMemsetAsync(deg, 0, N_NODES * sizeof(int), stream);

    k_hist<<<(N_EDGES + 255) / 256, 256, 0, stream>>>(dst, deg);
    k_blocksum<<<NB, 256, 0, stream>>>(deg, bsum);
    k_bsum_scan<<<1, 256, 0, stream>>>(bsum, boff, row_ptr);
    k_apply<<<NB, 256, 0, stream>>>(deg, boff, row_ptr, cursor);
    k_bucket<<<(N_EDGES + 255) / 256, 256, 0, stream>>>(src, dst, time_t, cursor, csr_src, csr_time);
    k_prep_w<<<256, 256, 0, stream>>>(fw, wT);
    k_node_time<<<(N_NODES + 3) / 4, 256, 0, stream>>>(h, csr_time, row_ptr, tw, tb, comb_bf);
    k_gemm_mfma<<<NP / 64, 256, 0, stream>>>(comb_bf, wT, al, ar, feat_bf, el, er);
    k_node_agg<<<N_NODES / 4, 256, 0, stream>>>(csr_src, row_ptr, feat_bf, comb_bf, el, er, out);
}

// Round 8
// 176.201 us; speedup vs baseline: 3.9404x; 1.1400x over previous
//
#include <hip/hip_runtime.h>
#include <hip/hip_bf16.h>
#include <math.h>

#define N_NODES 50000
#define NP      50048   // padded; multiple of 128 for the widened MFMA grid
#define N_EDGES 400000
#define IN_DIM  192
#define NB      196     // scan blocks: 196*256 = 50176 >= 50000

typedef float        f32x4 __attribute__((ext_vector_type(4)));
typedef unsigned int u32x4 __attribute__((ext_vector_type(4)));

__device__ __forceinline__ unsigned short f2bf(float f) {
    union { float f; unsigned int u; } v; v.f = f;
    unsigned int r = (v.u + 0x7FFF + ((v.u >> 16) & 1)) >> 16; // RNE
    return (unsigned short)r;
}
__device__ __forceinline__ float bf2f(unsigned short u) {
    union { unsigned int u; float f; } v; v.u = ((unsigned int)u) << 16;
    return v.f;
}
__device__ __forceinline__ float bfu_lo(unsigned int u) {
    union { unsigned int u; float f; } v; v.u = u << 16;
    return v.f;
}
__device__ __forceinline__ float bfu_hi(unsigned int u) {
    union { unsigned int u; float f; } v; v.u = u & 0xFFFF0000u;
    return v.f;
}

// D(16x16) += A(16x32,bf16) * B(32x16,bf16); a/b = 8 bf16 per lane (4 VGPRs).
// k-slot packing consistent between A and B -> correct by slot-pairing invariance.
#define MFMA_BF16(acc, a, b) \
    asm("v_mfma_f32_16x16x32_bf16 %0, %1, %2, %0" : "+v"(acc) : "v"(a), "v"(b))

// ---------------- CSR build ----------------
__global__ void k_hist(const int* __restrict__ dst, int* __restrict__ deg) {
    int e = blockIdx.x * 256 + threadIdx.x;
    if (e >= N_EDGES) return;
    atomicAdd(&deg[dst[e]], 1);
}

__global__ __launch_bounds__(256) void k_blocksum(const int* __restrict__ deg,
                                                  int* __restrict__ bsum) {
    int i = blockIdx.x * 256 + threadIdx.x;
    int v = (i < N_NODES) ? deg[i] : 0;
#pragma unroll
    for (int off = 32; off > 0; off >>= 1) v += __shfl_down(v, off, 64);
    __shared__ int ws[4];
    if ((threadIdx.x & 63) == 0) ws[threadIdx.x >> 6] = v;
    __syncthreads();
    if (threadIdx.x == 0) bsum[blockIdx.x] = ws[0] + ws[1] + ws[2] + ws[3];
}

__global__ __launch_bounds__(256) void k_bsum_scan(const int* __restrict__ bsum,
                                                   int* __restrict__ boff,
                                                   int* __restrict__ row_ptr) {
    __shared__ int part[256];
    int t = threadIdx.x;
    int v = (t < NB) ? bsum[t] : 0;
    part[t] = v;
    __syncthreads();
#pragma unroll
    for (int off = 1; off < 256; off <<= 1) {
        int u = (t >= off) ? part[t - off] : 0;
        __syncthreads();
        part[t] += u;
        __syncthreads();
    }
    if (t < NB) boff[t] = part[t] - v;       // exclusive block offset
    if (t == 255) row_ptr[N_NODES] = part[255];
}

__global__ __launch_bounds__(256) void k_apply(const int* __restrict__ deg,
                                               const int* __restrict__ boff,
                                               int* __restrict__ row_ptr,
                                               int* __restrict__ cursor) {
    __shared__ int part[256];
    int t = threadIdx.x;
    int i = blockIdx.x * 256 + t;
    int v = (i < N_NODES) ? deg[i] : 0;
    part[t] = v;
    __syncthreads();
#pragma unroll
    for (int off = 1; off < 256; off <<= 1) {
        int u = (t >= off) ? part[t - off] : 0;
        __syncthreads();
        part[t] += u;
        __syncthreads();
    }
    if (i < N_NODES) {
        int ex = boff[blockIdx.x] + part[t] - v;
        row_ptr[i] = ex;
        cursor[i] = ex;
    }
}

__global__ void k_bucket(const int* __restrict__ src, const int* __restrict__ dst,
                         const float* __restrict__ time_t, int* __restrict__ cursor,
                         int* __restrict__ csr_src, float* __restrict__ csr_time) {
    int e = blockIdx.x * 256 + threadIdx.x;
    if (e >= N_EDGES) return;
    int d = dst[e];
    int idx = atomicAdd(&cursor[d], 1);
    csr_src[idx] = src[e];
    csr_time[idx] = time_t[e];
}

// ---------------- fc_w -> bf16 W^T [n][k] ----------------
__global__ void k_prep_w(const float* __restrict__ fw, unsigned short* __restrict__ wT) {
    int n = blockIdx.x;
    int k = threadIdx.x;
    wT[n * 256 + k] = f2bf(fw[k * 256 + n]);
}

// ---------------- per-node time agg -> combined bf16 [NP][256] ----------------
__global__ void k_node_time(const float* __restrict__ h, const float* __restrict__ csr_time,
                            const int* __restrict__ row_ptr,
                            const float* __restrict__ tw, const float* __restrict__ tb,
                            unsigned short* __restrict__ comb) {
    int lane = threadIdx.x & 63;
    int d = blockIdx.x * 4 + (threadIdx.x >> 6);
    if (d >= N_NODES) return;
    int k0 = row_ptr[d], k1 = row_ptr[d + 1];
    float w = tw[lane], b = tb[lane];
    float s = 0.f;
    for (int k = k0; k < k1; ++k) s += __cosf(csr_time[k] * w + b);
    float mean = s / fmaxf((float)(k1 - k0), 1.0f);
    const float* hr = h + (size_t)d * IN_DIM;
    unsigned short* orow = comb + (size_t)d * 256;
    orow[lane]       = f2bf(hr[lane]);
    orow[lane + 64]  = f2bf(hr[lane + 64]);
    orow[lane + 128] = f2bf(hr[lane + 128]);
    orow[lane + 192] = f2bf(mean);
}

// ---------------- GEMM epilogue (R5-verbatim logic, factored) ----------------
__device__ __forceinline__ void gemm_epi(const f32x4 acc[16], int row_lo, int c,
                                         const float* __restrict__ al,
                                         const float* __restrict__ ar,
                                         unsigned short* __restrict__ feat,
                                         float* __restrict__ el,
                                         float* __restrict__ er) {
#pragma unroll
    for (int nt = 0; nt < 16; ++nt) {
#pragma unroll
        for (int reg = 0; reg < 4; ++reg) {
            feat[(size_t)(row_lo + reg) * 256 + nt * 16 + c] = f2bf(acc[nt][reg]);
        }
    }
#pragma unroll
    for (int hh = 0; hh < 4; ++hh) {
        float xl[4] = {0.f, 0.f, 0.f, 0.f};
        float xr[4] = {0.f, 0.f, 0.f, 0.f};
#pragma unroll
        for (int ntl = 0; ntl < 4; ++ntl) {
            int nt = hh * 4 + ntl;
            float av = al[nt * 16 + c];
            float rv = ar[nt * 16 + c];
#pragma unroll
            for (int reg = 0; reg < 4; ++reg) {
                xl[reg] += acc[nt][reg] * av;
                xr[reg] += acc[nt][reg] * rv;
            }
        }
#pragma unroll
        for (int reg = 0; reg < 4; ++reg) {
#pragma unroll
            for (int off = 1; off < 16; off <<= 1) {
                xl[reg] += __shfl_xor(xl[reg], off, 64);
                xr[reg] += __shfl_xor(xr[reg], off, 64);
            }
        }
        if (c == 0) {
#pragma unroll
            for (int reg = 0; reg < 4; ++reg) {
                el[(row_lo + reg) * 4 + hh] = xl[reg];
                er[(row_lo + reg) * 4 + hh] = xr[reg];
            }
        }
    }
}

// ---------------- MFMA GEMM: feat = combined @ fc_w ; fused el/er ----------------
// R5 structure, widened: each wave owns TWO 16-row tiles (r0 and r0+64); each
// loaded B fragment feeds 2 MFMAs -> half the B traffic, 2x MFMA per stall.
// B fragment math is R5-verbatim: b = wT[nt*16+c][ks*32+g*8].
__global__ __launch_bounds__(256) void k_gemm_mfma(
        const unsigned short* __restrict__ comb,  // [NP][256] bf16
        const unsigned short* __restrict__ wT,    // [256][256] bf16, [n][k]
        const float* __restrict__ al, const float* __restrict__ ar,
        unsigned short* __restrict__ feat,        // [NP][256] bf16
        float* __restrict__ el, float* __restrict__ er) {
    int lane = threadIdx.x & 63;
    int wave = threadIdx.x >> 6;
    int r0 = blockIdx.x * 128 + wave * 16;  // tile0: r0.., tile1: r0+64..
    int c = lane & 15;     // A row / B col within tile
    int g = lane >> 4;     // k-slot group

    f32x4 acc0[16], acc1[16];
#pragma unroll
    for (int nt = 0; nt < 16; ++nt) {
        acc0[nt] = (f32x4){0.f, 0.f, 0.f, 0.f};
        acc1[nt] = (f32x4){0.f, 0.f, 0.f, 0.f};
    }

    const unsigned short* arow0 = comb + (size_t)(r0 + c) * 256 + g * 8;
    const unsigned short* arow1 = comb + (size_t)(r0 + 64 + c) * 256 + g * 8;
    const unsigned short* brow  = wT + (size_t)c * 256 + g * 8;

    for (int ks = 0; ks < 8; ++ks) {
        u32x4 a0 = *(const u32x4*)(arow0 + ks * 32);
        u32x4 a1 = *(const u32x4*)(arow1 + ks * 32);
#pragma unroll
        for (int nt = 0; nt < 16; ++nt) {
            u32x4 b = *(const u32x4*)(brow + nt * 4096 + ks * 32);
            MFMA_BF16(acc0[nt], a0, b);
            MFMA_BF16(acc1[nt], a1, b);
        }
    }

    int row_lo = r0 + g * 4;  // lane holds rows row_lo..row_lo+3 of each tile
    gemm_epi(acc0, row_lo,      c, al, ar, feat, el, er);
    gemm_epi(acc1, row_lo + 64, c, al, ar, feat, el, er);
}

// ---------------- fused edge-softmax + message agg + residual + ELU ----------------
// Wave-synchronous: 1 wave = 1 node (4 nodes / 256-thread block).
#define CHUNK 64
__global__ __launch_bounds__(256) void k_node_agg(
        const int* __restrict__ csr_src, const int* __restrict__ row_ptr,
        const unsigned short* __restrict__ feat, const unsigned short* __restrict__ comb,
        const float* __restrict__ el, const float* __restrict__ er,
        float* __restrict__ out) {
    __shared__ float ex_lds[4][CHUNK * 4];
    __shared__ int   src_lds[4][CHUNK];
    int lane = threadIdx.x & 63;
    int wv   = threadIdx.x >> 6;
    int d = blockIdx.x * 4 + wv;           // grid = N/4 exact
    int k0 = row_ptr[d], k1 = row_ptr[d + 1];
    int j4 = lane >> 2, h4 = lane & 3;     // phase A: lane -> (edge-slot, head)
    int hh = lane >> 4;                    // phase B: head of owned cols
    float er_a = er[d * 4 + h4];
    float acc0 = 0.f, acc1 = 0.f, acc2 = 0.f, acc3 = 0.f, den_part = 0.f;

    for (int kc = k0; kc < k1; kc += CHUNK) {
        int cd = min(CHUNK, k1 - kc);
        for (int p = 0; p * 16 < cd; ++p) {
            int j = p * 16 + j4;
            if (j < cd) {
                int s = csr_src[kc + j];
                if (h4 == 0) src_lds[wv][j] = s;
                float v = el[s * 4 + h4] + er_a;
                v = v > 0.f ? v : 0.01f * v;
                float exv = __expf(v);
                ex_lds[wv][j * 4 + h4] = exv;
                den_part += exv;
            }
        }
#pragma unroll 2
        for (int j = 0; j < cd; ++j) {
            int s = src_lds[wv][j];
            float a = ex_lds[wv][j * 4 + hh];
            const uint2* fp = (const uint2*)(feat + (size_t)s * 256 + lane * 4);
            uint2 u = *fp;
            acc0 += bfu_lo(u.x) * a;
            acc1 += bfu_hi(u.x) * a;
            acc2 += bfu_lo(u.y) * a;
            acc3 += bfu_hi(u.y) * a;
        }
    }
    float dred = den_part;
    dred += __shfl_xor(dred, 4, 64);
    dred += __shfl_xor(dred, 8, 64);
    dred += __shfl_xor(dred, 16, 64);
    dred += __shfl_xor(dred, 32, 64);     // lane m now holds den[m&3]
    float den = __shfl(dred, hh, 64);     // lane hh (0..3) holds den[hh]
    float inv = 1.0f / fmaxf(den, 1e-16f);

    uint2 cb = *(const uint2*)(comb + (size_t)d * 256 + lane * 4);
    float x0 = bfu_lo(cb.x) + acc0 * inv;
    float x1 = bfu_hi(cb.x) + acc1 * inv;
    float x2 = bfu_lo(cb.y) + acc2 * inv;
    float x3 = bfu_hi(cb.y) + acc3 * inv;
    float4 o;
    o.x = x0 > 0.f ? x0 : expm1f(x0);
    o.y = x1 > 0.f ? x1 : expm1f(x1);
    o.z = x2 > 0.f ? x2 : expm1f(x2);
    o.w = x3 > 0.f ? x3 : expm1f(x3);
    *(float4*)&out[(size_t)d * 256 + lane * 4] = o;
}

extern "C" void kernel_launch(void* const* d_in, const int* in_sizes, int n_in,
                              void* d_out, int out_size, void* d_ws, size_t ws_size,
                              hipStream_t stream) {
    const float* h      = (const float*)d_in[0];
    const float* time_t = (const float*)d_in[1];
    const int*   src    = (const int*)d_in[2];
    const int*   dst    = (const int*)d_in[3];
    const float* tw     = (const float*)d_in[4];
    const float* tb     = (const float*)d_in[5];
    const float* fw     = (const float*)d_in[6];
    const float* al     = (const float*)d_in[7];
    const float* ar     = (const float*)d_in[8];
    float* out = (float*)d_out;

    // workspace layout (all segments 64B-aligned)
    char* p = (char*)d_ws;
    int*   deg      = (int*)p;                 p += 200000;          // N ints (zeroed)
    int*   row_ptr  = (int*)p;                 p += 200064;          // N+1 ints
    int*   cursor   = (int*)p;                                      // N ints
    unsigned short* wT = (unsigned short*)p;   p += 200000;          // wT aliases cursor (dead after bucket)
    int*   csr_src  = (int*)p;                 p += 1600000;         // E ints
    float* csr_time = (float*)p;               p += 1600000;         // E f32
    unsigned short* comb_bf = (unsigned short*)p; p += (size_t)NP * 512; // [NP][256] bf16
    unsigned short* feat_bf = (unsigned short*)p; p += (size_t)NP * 512; // [NP][256] bf16
    float* el       = (float*)p;               p += (size_t)NP * 16; // [NP][4]
    float* er       = (float*)p;               p += (size_t)NP * 16; // [NP][4]
    int*   bsum     = (int*)p;                 p += 256 * 4;         // NB block sums
    int*   boff     = (int*)p;                 p += 256 * 4;         // NB block offsets

    hipMemsetAsync(deg, 0, N_NODES * sizeof(int), stream);

    k_hist<<<(N_EDGES + 255) / 256, 256, 0, stream>>>(dst, deg);
    k_blocksum<<<NB, 256, 0, stream>>>(deg, bsum);
    k_bsum_scan<<<1, 256, 0, stream>>>(bsum, boff, row_ptr);
    k_apply<<<NB, 256, 0, stream>>>(deg, boff, row_ptr, cursor);
    k_bucket<<<(N_EDGES + 255) / 256, 256, 0, stream>>>(src, dst, time_t, cursor, csr_src, csr_time);
    k_prep_w<<<256, 256, 0, stream>>>(fw, wT);
    k_node_time<<<(N_NODES + 3) / 4, 256, 0, stream>>>(h, csr_time, row_ptr, tw, tb, comb_bf);
    k_gemm_mfma<<<NP / 128, 256, 0, stream>>>(comb_bf, wT, al, ar, feat_bf, el, er);
    k_node_agg<<<N_NODES / 4, 256, 0, stream>>>(csr_src, row_ptr, feat_bf, comb_bf, el, er, out);
}

// Round 9
// 167.776 us; speedup vs baseline: 4.1382x; 1.0502x over previous
//
#include <hip/hip_runtime.h>
#include <hip/hip_bf16.h>
#include <math.h>

#define N_NODES 50000
#define NP      50048   // padded; multiple of 128 for the MFMA grid
#define N_EDGES 400000
#define IN_DIM  192
#define NB      196     // scan blocks: 196*256 = 50176 >= 50000

typedef float        f32x4 __attribute__((ext_vector_type(4)));
typedef unsigned int u32x4 __attribute__((ext_vector_type(4)));

__device__ __forceinline__ unsigned short f2bf(float f) {
    union { float f; unsigned int u; } v; v.f = f;
    unsigned int r = (v.u + 0x7FFF + ((v.u >> 16) & 1)) >> 16; // RNE
    return (unsigned short)r;
}
__device__ __forceinline__ float bfu_lo(unsigned int u) {
    union { unsigned int u; float f; } v; v.u = u << 16;
    return v.f;
}
__device__ __forceinline__ float bfu_hi(unsigned int u) {
    union { unsigned int u; float f; } v; v.u = u & 0xFFFF0000u;
    return v.f;
}

// D(16x16) += A(16x32,bf16) * B(32x16,bf16); a/b = 8 bf16 per lane (4 VGPRs).
// k-slot packing consistent between A and B -> correct by slot-pairing invariance.
#define MFMA_BF16(acc, a, b) \
    asm("v_mfma_f32_16x16x32_bf16 %0, %1, %2, %0" : "+v"(acc) : "v"(a), "v"(b))

// ---------------- CSR build ----------------
__global__ void k_hist(const int* __restrict__ dst, int* __restrict__ deg) {
    int e = blockIdx.x * 256 + threadIdx.x;
    if (e >= N_EDGES) return;
    atomicAdd(&deg[dst[e]], 1);
}

__global__ __launch_bounds__(256) void k_blocksum(const int* __restrict__ deg,
                                                  int* __restrict__ bsum) {
    int i = blockIdx.x * 256 + threadIdx.x;
    int v = (i < N_NODES) ? deg[i] : 0;
#pragma unroll
    for (int off = 32; off > 0; off >>= 1) v += __shfl_down(v, off, 64);
    __shared__ int ws[4];
    if ((threadIdx.x & 63) == 0) ws[threadIdx.x >> 6] = v;
    __syncthreads();
    if (threadIdx.x == 0) bsum[blockIdx.x] = ws[0] + ws[1] + ws[2] + ws[3];
}

__global__ __launch_bounds__(256) void k_bsum_scan(const int* __restrict__ bsum,
                                                   int* __restrict__ boff,
                                                   int* __restrict__ row_ptr) {
    __shared__ int part[256];
    int t = threadIdx.x;
    int v = (t < NB) ? bsum[t] : 0;
    part[t] = v;
    __syncthreads();
#pragma unroll
    for (int off = 1; off < 256; off <<= 1) {
        int u = (t >= off) ? part[t - off] : 0;
        __syncthreads();
        part[t] += u;
        __syncthreads();
    }
    if (t < NB) boff[t] = part[t] - v;       // exclusive block offset
    if (t == 255) row_ptr[N_NODES] = part[255];
}

__global__ __launch_bounds__(256) void k_apply(const int* __restrict__ deg,
                                               const int* __restrict__ boff,
                                               int* __restrict__ row_ptr,
                                               int* __restrict__ cursor) {
    __shared__ int part[256];
    int t = threadIdx.x;
    int i = blockIdx.x * 256 + t;
    int v = (i < N_NODES) ? deg[i] : 0;
    part[t] = v;
    __syncthreads();
#pragma unroll
    for (int off = 1; off < 256; off <<= 1) {
        int u = (t >= off) ? part[t - off] : 0;
        __syncthreads();
        part[t] += u;
        __syncthreads();
    }
    if (i < N_NODES) {
        int ex = boff[blockIdx.x] + part[t] - v;
        row_ptr[i] = ex;
        cursor[i] = ex;
    }
}

__global__ void k_bucket(const int* __restrict__ src, const int* __restrict__ dst,
                         const float* __restrict__ time_t, int* __restrict__ cursor,
                         int* __restrict__ csr_src, float* __restrict__ csr_time) {
    int e = blockIdx.x * 256 + threadIdx.x;
    if (e >= N_EDGES) return;
    int d = dst[e];
    int idx = atomicAdd(&cursor[d], 1);
    csr_src[idx] = src[e];
    csr_time[idx] = time_t[e];
}

// ---------------- fc_w -> bf16 B-fragment order ----------------
// wF[((nt*8+ks)*64 + lane)*8 + j] = fc_w[ks*32 + g*8 + j][nt*16 + c],
// c=lane&15, g=lane>>4. A wave's b-load for (nt,ks) is then 64 consecutive
// 16B chunks (1KB contiguous) instead of 16 scattered cache lines.
__global__ void k_prep_w(const float* __restrict__ fw, unsigned short* __restrict__ wF) {
    int tid = blockIdx.x * 256 + threadIdx.x;   // 8192 threads
    int lane = tid & 63;
    int ks = (tid >> 6) & 7;
    int nt = tid >> 9;
    int c = lane & 15, g = lane >> 4;
    int n = nt * 16 + c;
    int k0 = ks * 32 + g * 8;
    union { unsigned short s[8]; u32x4 v; } u;
#pragma unroll
    for (int j = 0; j < 8; ++j) u.s[j] = f2bf(fw[(size_t)(k0 + j) * 256 + n]);
    *(u32x4*)(wF + (size_t)tid * 8) = u.v;
}

// ---------------- comb -> A-fragment order ----------------
// aF[((t*8+ks)*64 + lane)*8 + j] = comb[t*16 + c][ks*32 + g*8 + j].
// Scattered 16B reads, coalesced writes; 6256 blocks of TLP hide the latency.
__global__ __launch_bounds__(256) void k_prep_a(const unsigned short* __restrict__ comb,
                                                unsigned short* __restrict__ aF) {
    int tid = blockIdx.x * 256 + threadIdx.x;   // (t*8+ks)*64+lane
    int lane = tid & 63;
    int ks = (tid >> 6) & 7;
    int t = tid >> 9;
    int c = lane & 15, g = lane >> 4;
    u32x4 v = *(const u32x4*)(comb + (size_t)(t * 16 + c) * 256 + ks * 32 + g * 8);
    *(u32x4*)(aF + (size_t)tid * 8) = v;
}

// ---------------- per-node time agg -> combined bf16 [NP][256] ----------------
__global__ void k_node_time(const float* __restrict__ h, const float* __restrict__ csr_time,
                            const int* __restrict__ row_ptr,
                            const float* __restrict__ tw, const float* __restrict__ tb,
                            unsigned short* __restrict__ comb) {
    int lane = threadIdx.x & 63;
    int d = blockIdx.x * 4 + (threadIdx.x >> 6);
    if (d >= N_NODES) return;
    int k0 = row_ptr[d], k1 = row_ptr[d + 1];
    float w = tw[lane], b = tb[lane];
    float s = 0.f;
    for (int k = k0; k < k1; ++k) s += __cosf(csr_time[k] * w + b);
    float mean = s / fmaxf((float)(k1 - k0), 1.0f);
    const float* hr = h + (size_t)d * IN_DIM;
    unsigned short* orow = comb + (size_t)d * 256;
    orow[lane]       = f2bf(hr[lane]);
    orow[lane + 64]  = f2bf(hr[lane + 64]);
    orow[lane + 128] = f2bf(hr[lane + 128]);
    orow[lane + 192] = f2bf(mean);
}

// ---------------- GEMM epilogue (R5-verbatim logic, factored) ----------------
__device__ __forceinline__ void gemm_epi(const f32x4 acc[16], int row_lo, int c,
                                         const float* __restrict__ al,
                                         const float* __restrict__ ar,
                                         unsigned short* __restrict__ feat,
                                         float* __restrict__ el,
                                         float* __restrict__ er) {
#pragma unroll
    for (int nt = 0; nt < 16; ++nt) {
#pragma unroll
        for (int reg = 0; reg < 4; ++reg) {
            feat[(size_t)(row_lo + reg) * 256 + nt * 16 + c] = f2bf(acc[nt][reg]);
        }
    }
#pragma unroll
    for (int hh = 0; hh < 4; ++hh) {
        float xl[4] = {0.f, 0.f, 0.f, 0.f};
        float xr[4] = {0.f, 0.f, 0.f, 0.f};
#pragma unroll
        for (int ntl = 0; ntl < 4; ++ntl) {
            int nt = hh * 4 + ntl;
            float av = al[nt * 16 + c];
            float rv = ar[nt * 16 + c];
#pragma unroll
            for (int reg = 0; reg < 4; ++reg) {
                xl[reg] += acc[nt][reg] * av;
                xr[reg] += acc[nt][reg] * rv;
            }
        }
#pragma unroll
        for (int reg = 0; reg < 4; ++reg) {
#pragma unroll
            for (int off = 1; off < 16; off <<= 1) {
                xl[reg] += __shfl_xor(xl[reg], off, 64);
                xr[reg] += __shfl_xor(xr[reg], off, 64);
            }
        }
        if (c == 0) {
#pragma unroll
            for (int reg = 0; reg < 4; ++reg) {
                el[(row_lo + reg) * 4 + hh] = xl[reg];
                er[(row_lo + reg) * 4 + hh] = xr[reg];
            }
        }
    }
}

// ---------------- MFMA GEMM: feat = combined @ fc_w ; fused el/er ----------------
// R8 structure (2 row-tiles/wave), operands pre-swizzled to fragment order:
// every a/b load is 64 lanes x consecutive 16B = 1KB contiguous. Fragment
// contents per (wave,lane) are bit-identical to R8 -> same math.
__global__ __launch_bounds__(256) void k_gemm_mfma(
        const unsigned short* __restrict__ aF,    // fragment-ordered A
        const unsigned short* __restrict__ wF,    // fragment-ordered B
        const float* __restrict__ al, const float* __restrict__ ar,
        unsigned short* __restrict__ feat,        // [NP][256] bf16
        float* __restrict__ el, float* __restrict__ er) {
    int lane = threadIdx.x & 63;
    int wave = threadIdx.x >> 6;
    int t0 = blockIdx.x * 8 + wave;         // 16-row tile idx; tile1 = t0+4
    int r0 = t0 * 16;
    int c = lane & 15;
    int g = lane >> 4;

    f32x4 acc0[16], acc1[16];
#pragma unroll
    for (int nt = 0; nt < 16; ++nt) {
        acc0[nt] = (f32x4){0.f, 0.f, 0.f, 0.f};
        acc1[nt] = (f32x4){0.f, 0.f, 0.f, 0.f};
    }

    const unsigned short* a0p = aF + ((size_t)(t0 * 8) * 64 + lane) * 8;
    const unsigned short* a1p = aF + ((size_t)((t0 + 4) * 8) * 64 + lane) * 8;
    const unsigned short* bp  = wF + (size_t)lane * 8;

    for (int ks = 0; ks < 8; ++ks) {
        u32x4 a0 = *(const u32x4*)(a0p + ks * 512);
        u32x4 a1 = *(const u32x4*)(a1p + ks * 512);
#pragma unroll
        for (int nt = 0; nt < 16; ++nt) {
            u32x4 b = *(const u32x4*)(bp + (size_t)(nt * 8 + ks) * 512);
            MFMA_BF16(acc0[nt], a0, b);
            MFMA_BF16(acc1[nt], a1, b);
        }
    }

    int row_lo = r0 + g * 4;
    gemm_epi(acc0, row_lo,      c, al, ar, feat, el, er);
    gemm_epi(acc1, row_lo + 64, c, al, ar, feat, el, er);
}

// ---------------- fused edge-softmax + message agg + residual + ELU ----------------
// Wave-synchronous: 1 wave = 1 node (4 nodes / 256-thread block).
#define CHUNK 64
__global__ __launch_bounds__(256) void k_node_agg(
        const int* __restrict__ csr_src, const int* __restrict__ row_ptr,
        const unsigned short* __restrict__ feat, const unsigned short* __restrict__ comb,
        const float* __restrict__ el, const float* __restrict__ er,
        float* __restrict__ out) {
    __shared__ float ex_lds[4][CHUNK * 4];
    __shared__ int   src_lds[4][CHUNK];
    int lane = threadIdx.x & 63;
    int wv   = threadIdx.x >> 6;
    int d = blockIdx.x * 4 + wv;           // grid = N/4 exact
    int k0 = row_ptr[d], k1 = row_ptr[d + 1];
    int j4 = lane >> 2, h4 = lane & 3;     // phase A: lane -> (edge-slot, head)
    int hh = lane >> 4;                    // phase B: head of owned cols
    float er_a = er[d * 4 + h4];
    float acc0 = 0.f, acc1 = 0.f, acc2 = 0.f, acc3 = 0.f, den_part = 0.f;

    for (int kc = k0; kc < k1; kc += CHUNK) {
        int cd = min(CHUNK, k1 - kc);
        for (int p = 0; p * 16 < cd; ++p) {
            int j = p * 16 + j4;
            if (j < cd) {
                int s = csr_src[kc + j];
                if (h4 == 0) src_lds[wv][j] = s;
                float v = el[s * 4 + h4] + er_a;
                v = v > 0.f ? v : 0.01f * v;
                float exv = __expf(v);
                ex_lds[wv][j * 4 + h4] = exv;
                den_part += exv;
            }
        }
#pragma unroll 2
        for (int j = 0; j < cd; ++j) {
            int s = src_lds[wv][j];
            float a = ex_lds[wv][j * 4 + hh];
            const uint2* fp = (const uint2*)(feat + (size_t)s * 256 + lane * 4);
            uint2 u = *fp;
            acc0 += bfu_lo(u.x) * a;
            acc1 += bfu_hi(u.x) * a;
            acc2 += bfu_lo(u.y) * a;
            acc3 += bfu_hi(u.y) * a;
        }
    }
    float dred = den_part;
    dred += __shfl_xor(dred, 4, 64);
    dred += __shfl_xor(dred, 8, 64);
    dred += __shfl_xor(dred, 16, 64);
    dred += __shfl_xor(dred, 32, 64);     // lane m now holds den[m&3]
    float den = __shfl(dred, hh, 64);     // lane hh (0..3) holds den[hh]
    float inv = 1.0f / fmaxf(den, 1e-16f);

    uint2 cb = *(const uint2*)(comb + (size_t)d * 256 + lane * 4);
    float x0 = bfu_lo(cb.x) + acc0 * inv;
    float x1 = bfu_hi(cb.x) + acc1 * inv;
    float x2 = bfu_lo(cb.y) + acc2 * inv;
    float x3 = bfu_hi(cb.y) + acc3 * inv;
    float4 o;
    o.x = x0 > 0.f ? x0 : expm1f(x0);
    o.y = x1 > 0.f ? x1 : expm1f(x1);
    o.z = x2 > 0.f ? x2 : expm1f(x2);
    o.w = x3 > 0.f ? x3 : expm1f(x3);
    *(float4*)&out[(size_t)d * 256 + lane * 4] = o;
}

extern "C" void kernel_launch(void* const* d_in, const int* in_sizes, int n_in,
                              void* d_out, int out_size, void* d_ws, size_t ws_size,
                              hipStream_t stream) {
    const float* h      = (const float*)d_in[0];
    const float* time_t = (const float*)d_in[1];
    const int*   src    = (const int*)d_in[2];
    const int*   dst    = (const int*)d_in[3];
    const float* tw     = (const float*)d_in[4];
    const float* tb     = (const float*)d_in[5];
    const float* fw     = (const float*)d_in[6];
    const float* al     = (const float*)d_in[7];
    const float* ar     = (const float*)d_in[8];
    float* out = (float*)d_out;

    // workspace layout (all segments 64B-aligned)
    char* p = (char*)d_ws;
    int*   deg      = (int*)p;                 p += 200000;          // N ints (zeroed)
    int*   row_ptr  = (int*)p;                 p += 200064;          // N+1 ints
    int*   cursor   = (int*)p;                                      // N ints
    unsigned short* wF = (unsigned short*)p;   p += 200000;          // wF aliases cursor (dead after bucket)
    int*   csr_src  = (int*)p;                 p += 1600000;         // E ints
    float* csr_time = (float*)p;               p += 1600000;         // E f32
    unsigned short* comb_bf = (unsigned short*)p; p += (size_t)NP * 512; // [NP][256] bf16
    unsigned short* feat_bf = (unsigned short*)p; p += (size_t)NP * 512; // [NP][256] bf16
    unsigned short* aF      = (unsigned short*)p; p += (size_t)NP * 512; // fragment-ordered A
    float* el       = (float*)p;               p += (size_t)NP * 16; // [NP][4]
    float* er       = (float*)p;               p += (size_t)NP * 16; // [NP][4]
    int*   bsum     = (int*)p;                 p += 256 * 4;         // NB block sums
    int*   boff     = (int*)p;                 p += 256 * 4;         // NB block offsets

    hipMemsetAsync(deg, 0, N_NODES * sizeof(int), stream);

    k_hist<<<(N_EDGES + 255) / 256, 256, 0, stream>>>(dst, deg);
    k_blocksum<<<NB, 256, 0, stream>>>(deg, bsum);
    k_bsum_scan<<<1, 256, 0, stream>>>(bsum, boff, row_ptr);
    k_apply<<<NB, 256, 0, stream>>>(deg, boff, row_ptr, cursor);
    k_bucket<<<(N_EDGES + 255) / 256, 256, 0, stream>>>(src, dst, time_t, cursor, csr_src, csr_time);
    k_prep_w<<<32, 256, 0, stream>>>(fw, wF);
    k_node_time<<<(N_NODES + 3) / 4, 256, 0, stream>>>(h, csr_time, row_ptr, tw, tb, comb_bf);
    k_prep_a<<<(NP / 16) * 2, 256, 0, stream>>>(comb_bf, aF);
    k_gemm_mfma<<<NP / 128, 256, 0, stream>>>(aF, wF, al, ar, feat_bf, el, er);
    k_node_agg<<<N_NODES / 4, 256, 0, stream>>>(csr_src, row_ptr, feat_bf, comb_bf, el, er, out);
}